// Round 1
// baseline (366.198 us; speedup 1.0000x reference)
//
#include <hip/hip_runtime.h>
#include <hip/hip_bf16.h>

#define BB 32
#define LL 1024
#define DD 768

typedef short bf16x8 __attribute__((ext_vector_type(8)));
typedef float f32x4 __attribute__((ext_vector_type(4)));

// ---------------------------------------------------------------------------
// Pass 1: fp32 -> bf16 convert (Q and w3*K), plus q_logit / k_logit dots.
// One block (192 threads = 3 waves) per row; each thread owns one float4.
// ---------------------------------------------------------------------------
__device__ __forceinline__ unsigned short f2bf(float f) {
    // RNE f32->bf16 (inputs are finite normals; no NaN handling needed)
    unsigned u = __builtin_bit_cast(unsigned, f);
    u += 0x7fffu + ((u >> 16) & 1u);
    return (unsigned short)(u >> 16);
}

__global__ __launch_bounds__(192) void convert_kernel(
    const float* __restrict__ Q, const float* __restrict__ K,
    const float* __restrict__ w1, const float* __restrict__ w2,
    const float* __restrict__ w3,
    unsigned short* __restrict__ Qb, unsigned short* __restrict__ Kb,
    float* __restrict__ qlog, float* __restrict__ klog)
{
    const int row = blockIdx.x;           // 0 .. BB*LL-1
    const int t   = threadIdx.x;          // 0 .. 191 (192*4 = 768 = DD)
    const size_t base = (size_t)row * DD;

    float4 qv  = ((const float4*)(Q + base))[t];
    float4 kv  = ((const float4*)(K + base))[t];
    float4 w1v = ((const float4*)w1)[t];
    float4 w2v = ((const float4*)w2)[t];
    float4 w3v = ((const float4*)w3)[t];

    float qdot = qv.x*w1v.x + qv.y*w1v.y + qv.z*w1v.z + qv.w*w1v.w;
    float kdot = kv.x*w2v.x + kv.y*w2v.y + kv.z*w2v.z + kv.w*w2v.w;

    ushort4 pq, pk;
    pq.x = f2bf(qv.x); pq.y = f2bf(qv.y); pq.z = f2bf(qv.z); pq.w = f2bf(qv.w);
    pk.x = f2bf(kv.x * w3v.x); pk.y = f2bf(kv.y * w3v.y);
    pk.z = f2bf(kv.z * w3v.z); pk.w = f2bf(kv.w * w3v.w);
    ((ushort4*)(Qb + base))[t] = pq;
    ((ushort4*)(Kb + base))[t] = pk;

    // reduce qdot/kdot across 192 threads
    #pragma unroll
    for (int off = 32; off > 0; off >>= 1) {
        qdot += __shfl_down(qdot, off, 64);
        kdot += __shfl_down(kdot, off, 64);
    }
    __shared__ float sq[3], sk[3];
    const int wv = t >> 6, ln = t & 63;
    if (ln == 0) { sq[wv] = qdot; sk[wv] = kdot; }
    __syncthreads();
    if (t == 0) {
        qlog[row] = sq[0] + sq[1] + sq[2];
        klog[row] = sk[0] + sk[1] + sk[2];
    }
}

// ---------------------------------------------------------------------------
// Pass 2: batched GEMM  C[b] = Qb[b] @ Kb[b]^T  (+ q_logit row + k_logit col)
// m97 structure: 128x128 tile, BK=32, 256 thr = 4 waves in 2x2, each wave a
// 64x64 sub-tile = 4x4 MFMA accs of 16x16x32 bf16. global_load_lds width=16.
// ---------------------------------------------------------------------------
__global__ __launch_bounds__(256) void trilinear_gemm(
    const unsigned short* __restrict__ Qb, const unsigned short* __restrict__ Kb,
    const float* __restrict__ qlog, const float* __restrict__ klog,
    float* __restrict__ out)
{
    __shared__ __align__(16) unsigned short As[128 * 32];
    __shared__ __align__(16) unsigned short Bs[128 * 32];

    const int tid  = threadIdx.x;
    const int w    = tid >> 6, lane = tid & 63;
    const int wq   = w >> 1, wk = w & 1;
    const int b    = blockIdx.z, qt = blockIdx.y, kt = blockIdx.x;

    const unsigned short* Ag = Qb + ((size_t)b * LL + qt * 128) * DD;
    const unsigned short* Bg = Kb + ((size_t)b * LL + kt * 128) * DD;

    // staging: wave w stages rows [w*32, w*32+32) in two 16-row issues.
    // lane i -> row (i>>2), col (i&3)*8; LDS dest = base + i*16 B which is
    // exactly row-major [row][32] layout (64 B rows). (wave-uniform LDS base)
    const int srow0 = w * 32 + (lane >> 2);
    const int scol  = (lane & 3) * 8;
    const int m     = lane & 15;
    const int q8    = (lane >> 4) * 8;

    f32x4 acc[4][4] = {};

    for (int k0 = 0; k0 < DD; k0 += 32) {
        __syncthreads();   // prior iter's ds_reads done before overwrite
        #pragma unroll
        for (int j = 0; j < 2; ++j) {
            const int r = srow0 + j * 16;
            __builtin_amdgcn_global_load_lds(
                (const __attribute__((address_space(1))) void*)(Ag + (size_t)r * DD + k0 + scol),
                (__attribute__((address_space(3))) void*)&As[(w * 32 + j * 16) * 32],
                16, 0, 0);
            __builtin_amdgcn_global_load_lds(
                (const __attribute__((address_space(1))) void*)(Bg + (size_t)r * DD + k0 + scol),
                (__attribute__((address_space(3))) void*)&Bs[(w * 32 + j * 16) * 32],
                16, 0, 0);
        }
        __syncthreads();   // compiler drains vmcnt before this barrier

        bf16x8 av[4], bv[4];
        #pragma unroll
        for (int t = 0; t < 4; ++t) {
            av[t] = *(const bf16x8*)&As[(wq * 64 + t * 16 + m) * 32 + q8];
            bv[t] = *(const bf16x8*)&Bs[(wk * 64 + t * 16 + m) * 32 + q8];
        }
        #pragma unroll
        for (int at = 0; at < 4; ++at)
            #pragma unroll
            for (int bt = 0; bt < 4; ++bt)
                acc[at][bt] = __builtin_amdgcn_mfma_f32_16x16x32_bf16(
                    av[at], bv[bt], acc[at][bt], 0, 0, 0);
    }

    // epilogue: C/D layout col = lane&15, row = (lane>>4)*4 + reg  [m89/m91]
    const int qrow0 = qt * 128 + wq * 64;
    const int kcol0 = kt * 128 + wk * 64;
    const float* ql = qlog + b * LL + qrow0;
    const float* kl = klog + b * LL + kcol0;
    float* outp = out + ((size_t)b * LL + qrow0) * LL + kcol0;
    const int col = lane & 15, r4 = (lane >> 4) * 4;

    #pragma unroll
    for (int at = 0; at < 4; ++at) {
        #pragma unroll
        for (int bt = 0; bt < 4; ++bt) {
            const float klv = kl[bt * 16 + col];
            #pragma unroll
            for (int r = 0; r < 4; ++r) {
                const int row = at * 16 + r4 + r;
                outp[(size_t)row * LL + bt * 16 + col] = acc[at][bt][r] + ql[row] + klv;
            }
        }
    }
}

extern "C" void kernel_launch(void* const* d_in, const int* in_sizes, int n_in,
                              void* d_out, int out_size, void* d_ws, size_t ws_size,
                              hipStream_t stream) {
    const float* Q  = (const float*)d_in[0];
    const float* K  = (const float*)d_in[1];
    const float* w1 = (const float*)d_in[2];
    const float* w2 = (const float*)d_in[3];
    const float* w3 = (const float*)d_in[4];
    float* out = (float*)d_out;

    // workspace layout: Qb (bf16), Kb (bf16 of w3*K), qlog, klog
    unsigned short* Qb = (unsigned short*)d_ws;
    unsigned short* Kb = Qb + (size_t)BB * LL * DD;
    float* qlog = (float*)(Kb + (size_t)BB * LL * DD);
    float* klog = qlog + BB * LL;

    convert_kernel<<<BB * LL, 192, 0, stream>>>(Q, K, w1, w2, w3, Qb, Kb, qlog, klog);
    trilinear_gemm<<<dim3(8, 8, BB), 256, 0, stream>>>(Qb, Kb, qlog, klog, out);
}

// Round 2
// 364.176 us; speedup vs baseline: 1.0056x; 1.0056x over previous
//
#include <hip/hip_runtime.h>
#include <hip/hip_bf16.h>

#define BB 32
#define LL 1024
#define DD 768

typedef short bf16x8 __attribute__((ext_vector_type(8)));
typedef float f32x4 __attribute__((ext_vector_type(4)));

// ---------------------------------------------------------------------------
// Pass 1: fp32 -> bf16 convert (Q and w3*K), plus q_logit / k_logit dots.
// One wave per row (256-thr blocks = 4 rows/block); lane owns 3 float4 chunks
// at stride 64 (768 floats = 192 float4 = 64 lanes x 3). Shuffle-only reduce.
// ---------------------------------------------------------------------------
__device__ __forceinline__ unsigned short f2bf(float f) {
    // RNE f32->bf16 (inputs are finite normals; no NaN handling needed)
    unsigned u = __builtin_bit_cast(unsigned, f);
    u += 0x7fffu + ((u >> 16) & 1u);
    return (unsigned short)(u >> 16);
}

__global__ __launch_bounds__(256) void convert_kernel(
    const float* __restrict__ Q, const float* __restrict__ K,
    const float* __restrict__ w1, const float* __restrict__ w2,
    const float* __restrict__ w3,
    unsigned short* __restrict__ Qb, unsigned short* __restrict__ Kb,
    float* __restrict__ qlog, float* __restrict__ klog)
{
    const int ln  = threadIdx.x & 63;
    const int row = blockIdx.x * 4 + (threadIdx.x >> 6);
    const size_t base = (size_t)row * DD;

    float qdot = 0.f, kdot = 0.f;
    #pragma unroll
    for (int c = 0; c < 3; ++c) {
        const int idx = c * 64 + ln;  // float4 index within the row
        float4 qv  = ((const float4*)(Q + base))[idx];
        float4 kv  = ((const float4*)(K + base))[idx];
        float4 w1v = ((const float4*)w1)[idx];
        float4 w2v = ((const float4*)w2)[idx];
        float4 w3v = ((const float4*)w3)[idx];

        qdot += qv.x*w1v.x + qv.y*w1v.y + qv.z*w1v.z + qv.w*w1v.w;
        kdot += kv.x*w2v.x + kv.y*w2v.y + kv.z*w2v.z + kv.w*w2v.w;

        ushort4 pq, pk;
        pq.x = f2bf(qv.x); pq.y = f2bf(qv.y); pq.z = f2bf(qv.z); pq.w = f2bf(qv.w);
        pk.x = f2bf(kv.x * w3v.x); pk.y = f2bf(kv.y * w3v.y);
        pk.z = f2bf(kv.z * w3v.z); pk.w = f2bf(kv.w * w3v.w);
        ((ushort4*)(Qb + base))[idx] = pq;
        ((ushort4*)(Kb + base))[idx] = pk;
    }

    #pragma unroll
    for (int off = 32; off > 0; off >>= 1) {
        qdot += __shfl_down(qdot, off, 64);
        kdot += __shfl_down(kdot, off, 64);
    }
    if (ln == 0) { qlog[row] = qdot; klog[row] = kdot; }
}

// ---------------------------------------------------------------------------
// Pass 2: batched GEMM  C[b] = Qb[b] @ Kb[b]^T  (+ q_logit row + k_logit col)
// 128x128 tile, BK=32, 4 waves in 2x2, 4x4 accs of 16x16x32 bf16 MFMA.
// LDS layout is XOR-swizzled to kill ds_read_b128 bank conflicts while
// staying compatible with global_load_lds's lane-ordered destination:
//   physical 16B block p of row r holds logical k-block l = p ^ ((r>>1)&3).
// Staging lane i (slot = base + i*16, row r = i>>2, phys p = i&3) therefore
// fetches global columns ((i&3)^((i>>3)&3))*8. Fragment readers use
// p = l ^ ((m>>1)&3) (lane-invariant). Result: 16-row fragment reads spread
// over all 8 bank groups exactly 2x (2-way = free, m136), staging stays
// fully coalesced (contiguous 64B row segments, lane-permuted).
// ---------------------------------------------------------------------------
__global__ __launch_bounds__(256) void trilinear_gemm(
    const unsigned short* __restrict__ Qb, const unsigned short* __restrict__ Kb,
    const float* __restrict__ qlog, const float* __restrict__ klog,
    float* __restrict__ out)
{
    __shared__ __align__(16) unsigned short As[128 * 32];
    __shared__ __align__(16) unsigned short Bs[128 * 32];

    const int tid  = threadIdx.x;
    const int w    = tid >> 6, lane = tid & 63;
    const int wq   = w >> 1, wk = w & 1;
    const int b    = blockIdx.z, qt = blockIdx.y, kt = blockIdx.x;

    const unsigned short* Ag = Qb + ((size_t)b * LL + qt * 128) * DD;
    const unsigned short* Bg = Kb + ((size_t)b * LL + kt * 128) * DD;

    // staging addresses (swizzled column pick per lane)
    const int srow  = lane >> 2;                         // 0..15 within issue
    const int scol  = ((lane & 3) ^ ((lane >> 3) & 3)) * 8;  // swizzled k-chunk
    // fragment-read constants
    const int m    = lane & 15;
    const int l    = lane >> 4;                          // logical k-block
    const int p8   = (l ^ ((m >> 1) & 3)) * 8;           // physical k-chunk

    f32x4 acc[4][4] = {};

    for (int k0 = 0; k0 < DD; k0 += 32) {
        __syncthreads();   // prior iter's ds_reads done before overwrite
        #pragma unroll
        for (int j = 0; j < 2; ++j) {
            const int r = w * 32 + j * 16 + srow;
            __builtin_amdgcn_global_load_lds(
                (const __attribute__((address_space(1))) void*)(Ag + (size_t)r * DD + k0 + scol),
                (__attribute__((address_space(3))) void*)&As[(w * 32 + j * 16) * 32],
                16, 0, 0);
            __builtin_amdgcn_global_load_lds(
                (const __attribute__((address_space(1))) void*)(Bg + (size_t)r * DD + k0 + scol),
                (__attribute__((address_space(3))) void*)&Bs[(w * 32 + j * 16) * 32],
                16, 0, 0);
        }
        __syncthreads();   // compiler drains vmcnt before this barrier

        bf16x8 av[4], bv[4];
        #pragma unroll
        for (int t = 0; t < 4; ++t) {
            av[t] = *(const bf16x8*)&As[(wq * 64 + t * 16 + m) * 32 + p8];
            bv[t] = *(const bf16x8*)&Bs[(wk * 64 + t * 16 + m) * 32 + p8];
        }
        #pragma unroll
        for (int at = 0; at < 4; ++at)
            #pragma unroll
            for (int bt = 0; bt < 4; ++bt)
                acc[at][bt] = __builtin_amdgcn_mfma_f32_16x16x32_bf16(
                    av[at], bv[bt], acc[at][bt], 0, 0, 0);
    }

    // epilogue: C/D layout col = lane&15, row = (lane>>4)*4 + reg  [m89/m91]
    const int qrow0 = qt * 128 + wq * 64;
    const int kcol0 = kt * 128 + wk * 64;
    const float* ql = qlog + b * LL + qrow0;
    const float* kl = klog + b * LL + kcol0;
    float* outp = out + ((size_t)b * LL + qrow0) * LL + kcol0;
    const int col = lane & 15, r4 = (lane >> 4) * 4;

    #pragma unroll
    for (int at = 0; at < 4; ++at) {
        #pragma unroll
        for (int bt = 0; bt < 4; ++bt) {
            const float klv = kl[bt * 16 + col];
            #pragma unroll
            for (int r = 0; r < 4; ++r) {
                const int row = at * 16 + r4 + r;
                outp[(size_t)row * LL + bt * 16 + col] = acc[at][bt][r] + ql[row] + klv;
            }
        }
    }
}

extern "C" void kernel_launch(void* const* d_in, const int* in_sizes, int n_in,
                              void* d_out, int out_size, void* d_ws, size_t ws_size,
                              hipStream_t stream) {
    const float* Q  = (const float*)d_in[0];
    const float* K  = (const float*)d_in[1];
    const float* w1 = (const float*)d_in[2];
    const float* w2 = (const float*)d_in[3];
    const float* w3 = (const float*)d_in[4];
    float* out = (float*)d_out;

    // workspace layout: Qb (bf16), Kb (bf16 of w3*K), qlog, klog
    unsigned short* Qb = (unsigned short*)d_ws;
    unsigned short* Kb = Qb + (size_t)BB * LL * DD;
    float* qlog = (float*)(Kb + (size_t)BB * LL * DD);
    float* klog = qlog + BB * LL;

    convert_kernel<<<BB * LL / 4, 256, 0, stream>>>(Q, K, w1, w2, w3, Qb, Kb, qlog, klog);
    trilinear_gemm<<<dim3(8, 8, BB), 256, 0, stream>>>(Qb, Kb, qlog, klog, out);
}

// Round 3
// 356.580 us; speedup vs baseline: 1.0270x; 1.0213x over previous
//
#include <hip/hip_runtime.h>
#include <hip/hip_bf16.h>

#define BB 32
#define LL 1024
#define DD 768

typedef short bf16x8 __attribute__((ext_vector_type(8)));
typedef float f32x4 __attribute__((ext_vector_type(4)));

// ---------------------------------------------------------------------------
// Pass 1: fp32 -> bf16 convert (Q and w3*K), plus q_logit / k_logit dots.
// One wave per row (256-thr blocks = 4 rows/block); lane owns 3 float4 chunks
// at stride 64 (768 floats = 192 float4 = 64 lanes x 3). Shuffle-only reduce.
// ---------------------------------------------------------------------------
__device__ __forceinline__ unsigned short f2bf(float f) {
    // RNE f32->bf16 (inputs are finite normals; no NaN handling needed)
    unsigned u = __builtin_bit_cast(unsigned, f);
    u += 0x7fffu + ((u >> 16) & 1u);
    return (unsigned short)(u >> 16);
}

__global__ __launch_bounds__(256) void convert_kernel(
    const float* __restrict__ Q, const float* __restrict__ K,
    const float* __restrict__ w1, const float* __restrict__ w2,
    const float* __restrict__ w3,
    unsigned short* __restrict__ Qb, unsigned short* __restrict__ Kb,
    float* __restrict__ qlog, float* __restrict__ klog)
{
    const int ln  = threadIdx.x & 63;
    const int row = blockIdx.x * 4 + (threadIdx.x >> 6);
    const size_t base = (size_t)row * DD;

    float qdot = 0.f, kdot = 0.f;
    #pragma unroll
    for (int c = 0; c < 3; ++c) {
        const int idx = c * 64 + ln;  // float4 index within the row
        float4 qv  = ((const float4*)(Q + base))[idx];
        float4 kv  = ((const float4*)(K + base))[idx];
        float4 w1v = ((const float4*)w1)[idx];
        float4 w2v = ((const float4*)w2)[idx];
        float4 w3v = ((const float4*)w3)[idx];

        qdot += qv.x*w1v.x + qv.y*w1v.y + qv.z*w1v.z + qv.w*w1v.w;
        kdot += kv.x*w2v.x + kv.y*w2v.y + kv.z*w2v.z + kv.w*w2v.w;

        ushort4 pq, pk;
        pq.x = f2bf(qv.x); pq.y = f2bf(qv.y); pq.z = f2bf(qv.z); pq.w = f2bf(qv.w);
        pk.x = f2bf(kv.x * w3v.x); pk.y = f2bf(kv.y * w3v.y);
        pk.z = f2bf(kv.z * w3v.z); pk.w = f2bf(kv.w * w3v.w);
        ((ushort4*)(Qb + base))[idx] = pq;
        ((ushort4*)(Kb + base))[idx] = pk;
    }

    #pragma unroll
    for (int off = 32; off > 0; off >>= 1) {
        qdot += __shfl_down(qdot, off, 64);
        kdot += __shfl_down(kdot, off, 64);
    }
    if (ln == 0) { qlog[row] = qdot; klog[row] = kdot; }
}

// ---------------------------------------------------------------------------
// Pass 2: batched GEMM  C[b] = Qb[b] @ Kb[b]^T  (+ q_logit row + k_logit col)
// 128x128 tile, BK=32, 4 waves in 2x2, 4x4 accs of 16x16x32 bf16 MFMA.
//
// Grid is 1-D with a batch->XCD affinity swizzle: all 64 tiles of batch b get
// linear ids == b (mod 8), so (assuming round-robin id%8 -> XCD dispatch) one
// batch's Qb+Kb slice (3 MB) lives in ONE XCD's 4 MB L2 while its 64 blocks
// run. qt-major order within the batch makes consecutive same-XCD blocks
// share an A-tile. Even if the XCD mapping heuristic is off, the reuse
// distance shrinks enough for L3 to absorb the 8x tile re-reads.
//
// LDS layout is XOR-swizzled (R2: verified SQ_LDS_BANK_CONFLICT = 0) and
// compatible with global_load_lds's lane-ordered destination:
//   physical 16B block p of row r holds logical k-block l = p ^ ((r>>1)&3).
// ---------------------------------------------------------------------------
__global__ __launch_bounds__(256) void trilinear_gemm(
    const unsigned short* __restrict__ Qb, const unsigned short* __restrict__ Kb,
    const float* __restrict__ qlog, const float* __restrict__ klog,
    float* __restrict__ out)
{
    __shared__ __align__(16) unsigned short As[128 * 32];
    __shared__ __align__(16) unsigned short Bs[128 * 32];

    const int tid  = threadIdx.x;
    const int w    = tid >> 6, lane = tid & 63;
    const int wq   = w >> 1, wk = w & 1;

    // batch->XCD swizzle: id = g + 8*(t + 64*(b>>3)), g = b&7, t = qt*8+kt
    const int id = blockIdx.x;
    const int g  = id & 7;
    const int j  = id >> 3;            // 0..255
    const int b  = g + ((j >> 6) << 3);
    const int t0 = j & 63;
    const int qt = t0 >> 3, kt = t0 & 7;

    const unsigned short* Ag = Qb + ((size_t)b * LL + qt * 128) * DD;
    const unsigned short* Bg = Kb + ((size_t)b * LL + kt * 128) * DD;

    // staging addresses (swizzled column pick per lane)
    const int srow  = lane >> 2;                         // 0..15 within issue
    const int scol  = ((lane & 3) ^ ((lane >> 3) & 3)) * 8;  // swizzled k-chunk
    // fragment-read constants
    const int m    = lane & 15;
    const int l    = lane >> 4;                          // logical k-block
    const int p8   = (l ^ ((m >> 1) & 3)) * 8;           // physical k-chunk

    f32x4 acc[4][4] = {};

    for (int k0 = 0; k0 < DD; k0 += 32) {
        __syncthreads();   // prior iter's ds_reads done before overwrite
        #pragma unroll
        for (int j2 = 0; j2 < 2; ++j2) {
            const int r = w * 32 + j2 * 16 + srow;
            __builtin_amdgcn_global_load_lds(
                (const __attribute__((address_space(1))) void*)(Ag + (size_t)r * DD + k0 + scol),
                (__attribute__((address_space(3))) void*)&As[(w * 32 + j2 * 16) * 32],
                16, 0, 0);
            __builtin_amdgcn_global_load_lds(
                (const __attribute__((address_space(1))) void*)(Bg + (size_t)r * DD + k0 + scol),
                (__attribute__((address_space(3))) void*)&Bs[(w * 32 + j2 * 16) * 32],
                16, 0, 0);
        }
        __syncthreads();   // compiler drains vmcnt before this barrier

        bf16x8 av[4], bv[4];
        #pragma unroll
        for (int tt = 0; tt < 4; ++tt) {
            av[tt] = *(const bf16x8*)&As[(wq * 64 + tt * 16 + m) * 32 + p8];
            bv[tt] = *(const bf16x8*)&Bs[(wk * 64 + tt * 16 + m) * 32 + p8];
        }
        #pragma unroll
        for (int at = 0; at < 4; ++at)
            #pragma unroll
            for (int bt = 0; bt < 4; ++bt)
                acc[at][bt] = __builtin_amdgcn_mfma_f32_16x16x32_bf16(
                    av[at], bv[bt], acc[at][bt], 0, 0, 0);
    }

    // epilogue: C/D layout col = lane&15, row = (lane>>4)*4 + reg  [m89/m91]
    const int qrow0 = qt * 128 + wq * 64;
    const int kcol0 = kt * 128 + wk * 64;
    const float* ql = qlog + b * LL + qrow0;
    const float* kl = klog + b * LL + kcol0;
    float* outp = out + ((size_t)b * LL + qrow0) * LL + kcol0;
    const int col = lane & 15, r4 = (lane >> 4) * 4;

    #pragma unroll
    for (int at = 0; at < 4; ++at) {
        #pragma unroll
        for (int bt = 0; bt < 4; ++bt) {
            const float klv = kl[bt * 16 + col];
            #pragma unroll
            for (int r = 0; r < 4; ++r) {
                const int row = at * 16 + r4 + r;
                outp[(size_t)row * LL + bt * 16 + col] = acc[at][bt][r] + ql[row] + klv;
            }
        }
    }
}

extern "C" void kernel_launch(void* const* d_in, const int* in_sizes, int n_in,
                              void* d_out, int out_size, void* d_ws, size_t ws_size,
                              hipStream_t stream) {
    const float* Q  = (const float*)d_in[0];
    const float* K  = (const float*)d_in[1];
    const float* w1 = (const float*)d_in[2];
    const float* w2 = (const float*)d_in[3];
    const float* w3 = (const float*)d_in[4];
    float* out = (float*)d_out;

    // workspace layout: Qb (bf16), Kb (bf16 of w3*K), qlog, klog
    unsigned short* Qb = (unsigned short*)d_ws;
    unsigned short* Kb = Qb + (size_t)BB * LL * DD;
    float* qlog = (float*)(Kb + (size_t)BB * LL * DD);
    float* klog = qlog + BB * LL;

    convert_kernel<<<BB * LL / 4, 256, 0, stream>>>(Q, K, w1, w2, w3, Qb, Kb, qlog, klog);
    trilinear_gemm<<<2048, 256, 0, stream>>>(Qb, Kb, qlog, klog, out);
}